// Round 2
// baseline (897.918 us; speedup 1.0000x reference)
//
#include <hip/hip_runtime.h>

typedef __bf16 bf16;
typedef __bf16 bf16x8 __attribute__((ext_vector_type(8)));
typedef float  f32x4  __attribute__((ext_vector_type(4)));

#define NB 4
#define NT 2048
#define NC 512
#define NV 32000
#define NROWS (NB*NT)          // 8192
#define NCHUNK (NV/256)        // 125
#define LNEPS 1e-5f
#define SMEM_B 131072

static __device__ __forceinline__ void load_lds16(const bf16* g, char* l) {
  __builtin_amdgcn_global_load_lds(
      (const __attribute__((address_space(1))) void*)g,
      (__attribute__((address_space(3))) void*)l, 16, 0, 0);
}

static __device__ __forceinline__ void bar() {
  asm volatile("" ::: "memory");
  __builtin_amdgcn_s_barrier();
  asm volatile("" ::: "memory");
}

// ---------------- f32 -> bf16 convert (vectorized x8) ----------------
__global__ __launch_bounds__(256)
void cvt_kernel(const float* __restrict__ in, bf16* __restrict__ out, int n8) {
  long i = (long)blockIdx.x * 256 + threadIdx.x;
  long stride = (long)gridDim.x * 256;
  for (; i < n8; i += stride) {
    const float* p = in + i * 8;
    f32x4 a = *(const f32x4*)p;
    f32x4 b = *(const f32x4*)(p + 4);
    bf16x8 o;
    o[0]=(bf16)a.x; o[1]=(bf16)a.y; o[2]=(bf16)a.z; o[3]=(bf16)a.w;
    o[4]=(bf16)b.x; o[5]=(bf16)b.y; o[6]=(bf16)b.z; o[7]=(bf16)b.w;
    *(bf16x8*)(out + i*8) = o;
  }
}

// ---------------- embedding ----------------
__global__ __launch_bounds__(64)
void embed_kernel(const int* __restrict__ idx, const float* __restrict__ tok,
                  const float* __restrict__ pos, float* __restrict__ x0) {
  int row = blockIdx.x;
  int t = row & (NT-1);
  int id = idx[row];
  int lane = threadIdx.x;
  const float* tr = tok + (long)id*NC + lane*8;
  const float* pr = pos + (long)t*NC + lane*8;
  f32x4 a0 = *(const f32x4*)tr, a1 = *(const f32x4*)(tr+4);
  f32x4 p0 = *(const f32x4*)pr, p1 = *(const f32x4*)(pr+4);
  f32x4 r0 = a0 + p0, r1 = a1 + p1;
  float* o = x0 + (long)row*NC + lane*8;
  *(f32x4*)o = r0; *(f32x4*)(o+4) = r1;
}

// ---------------- layernorm: one wave per row of 512 ----------------
__global__ __launch_bounds__(64)
void ln_kernel(const float* __restrict__ x, const float* __restrict__ gw,
               const float* __restrict__ bw, bf16* __restrict__ out) {
  int row = blockIdx.x;
  int lane = threadIdx.x;
  const float* xr = x + (long)row*NC + lane*8;
  f32x4 a = *(const f32x4*)xr;
  f32x4 b = *(const f32x4*)(xr+4);
  float v[8] = {a.x,a.y,a.z,a.w,b.x,b.y,b.z,b.w};
  float s = 0.f;
  #pragma unroll
  for (int j=0;j<8;++j) s += v[j];
  #pragma unroll
  for (int m=32;m>=1;m>>=1) s += __shfl_xor(s, m);
  float mu = s * (1.f/NC);
  float sq = 0.f;
  #pragma unroll
  for (int j=0;j<8;++j) { v[j] -= mu; sq += v[j]*v[j]; }
  #pragma unroll
  for (int m=32;m>=1;m>>=1) sq += __shfl_xor(sq, m);
  float rs = rsqrtf(sq * (1.f/NC) + LNEPS);
  const float* gp = gw + lane*8;
  const float* bp = bw + lane*8;
  f32x4 g0 = *(const f32x4*)gp, g1 = *(const f32x4*)(gp+4);
  f32x4 b0 = *(const f32x4*)bp, b1 = *(const f32x4*)(bp+4);
  float gg[8] = {g0.x,g0.y,g0.z,g0.w,g1.x,g1.y,g1.z,g1.w};
  float bb[8] = {b0.x,b0.y,b0.z,b0.w,b1.x,b1.y,b1.z,b1.w};
  bf16x8 o;
  #pragma unroll
  for (int j=0;j<8;++j) o[j] = (bf16)(v[j]*rs*gg[j] + bb[j]);
  *(bf16x8*)(out + (long)row*NC + lane*8) = o;
}

// ---------------- transpose v[b][t][c] (stride ldv) -> vt[b][c][t] ----------------
__global__ __launch_bounds__(256)
void transpose_kernel(const bf16* __restrict__ v, long ldv, bf16* __restrict__ vt) {
  __shared__ bf16 tile[64][66];
  int b = blockIdx.z;
  int t0 = blockIdx.x*64, c0 = blockIdx.y*64;
  int tid = threadIdx.x;
  int r = tid >> 2, ch = (tid & 3) * 16;
  const bf16* src = v + ((long)b*NT + t0 + r)*ldv + c0 + ch;
  #pragma unroll
  for (int i=0;i<16;++i) tile[r][ch+i] = src[i];
  __syncthreads();
  bf16x8 o0, o1;
  #pragma unroll
  for (int i=0;i<8;++i) o0[i] = tile[ch+i][r];
  #pragma unroll
  for (int i=0;i<8;++i) o1[i] = tile[ch+8+i][r];
  bf16* dst = vt + ((long)b*NC + c0 + r)*NT + t0 + ch;
  *(bf16x8*)dst = o0;
  *(bf16x8*)(dst+8) = o1;
}

// ---------------- causal softmax row: S f32 -> P bf16 (aliased into S) ----------------
__global__ __launch_bounds__(256)
void softmax_kernel(float* __restrict__ S) {
  const int row = blockIdx.x;
  const int t = row & (NT-1);
  const int tid = threadIdx.x;
  float* sr = S + (long)row*NT;
  bf16* pr = (bf16*)S + (long)row*(2*NT);
  const float scale = 0.044194173824159216f;
  f32x4 v0 = *(const f32x4*)(sr + tid*8);
  f32x4 v1 = *(const f32x4*)(sr + tid*8 + 4);
  float v[8] = {v0.x,v0.y,v0.z,v0.w,v1.x,v1.y,v1.z,v1.w};
  int cb = tid*8;
  float mx = -1e30f;
  #pragma unroll
  for (int j=0;j<8;++j) {
    v[j] = (cb + j <= t) ? v[j]*scale : -1e30f;
    mx = fmaxf(mx, v[j]);
  }
  __shared__ float redm[4];
  #pragma unroll
  for (int m=32;m>=1;m>>=1) mx = fmaxf(mx, __shfl_xor(mx, m));
  if ((tid & 63) == 0) redm[tid>>6] = mx;
  __syncthreads();
  mx = fmaxf(fmaxf(redm[0],redm[1]), fmaxf(redm[2],redm[3]));
  float e[8]; float s = 0.f;
  #pragma unroll
  for (int j=0;j<8;++j) { e[j] = (cb + j <= t) ? __expf(v[j]-mx) : 0.f; s += e[j]; }
  __shared__ float reds[4];
  #pragma unroll
  for (int m=32;m>=1;m>>=1) s += __shfl_xor(s, m);
  if ((tid & 63) == 0) reds[tid>>6] = s;
  __syncthreads();
  s = reds[0]+reds[1]+reds[2]+reds[3];
  float inv = 1.f/s;
  bf16x8 o;
  #pragma unroll
  for (int j=0;j<8;++j) o[j] = (bf16)(e[j]*inv);
  *(bf16x8*)(pr + cb) = o;
}

// ======== 256x256-tile 8-phase GEMM: out[M,N] = A[M,K] * B[N,K]^T ========
// 512 threads = 8 waves (2 wr x 4 wc); per-wave 128x64 out; BK=64; LDS 128KB
// (2 slots x (A 32KB + B 32KB)); st_16x32 swizzle; counted vmcnt(2) at P4/P8.
enum { EPI_F32=0, EPI_BF16=1, EPI_BIAS_RELU_BF16=2, EPI_BIAS_RES_BF16=3, EPI_RES_F32=4, EPI_LMHEAD=5 };

template<int EPI, bool CAUSAL=false, bool KLIMIT=false, bool SWZ=false>
__global__ __launch_bounds__(512,2)
void gemm256(const bf16* __restrict__ A, const bf16* __restrict__ B, int nkt,
             long lda, long ldb, long sAb, long sBb,
             float* __restrict__ outf, bf16* __restrict__ outb, long ldo, long sOb,
             const float* __restrict__ bias,
             const float* __restrict__ res, long ldr, long sRb,
             float* __restrict__ pmax, float* __restrict__ psum) {
  extern __shared__ char smem[];
  int bn = blockIdx.x, bm = blockIdx.y;
  const int bz = blockIdx.z;
  if constexpr (SWZ) {
    int gx = gridDim.x, nwg = gx * gridDim.y;
    int flat = bm * gx + bn;
    int q = nwg >> 3, r = nwg & 7;
    int xcd = flat & 7, pos = flat >> 3;
    int wgid = (xcd < r ? xcd*(q+1) : r*(q+1) + (xcd-r)*q) + pos;
    bn = wgid % gx; bm = wgid / gx;
  }
  if constexpr (CAUSAL) { if (bn > bm) return; }
  int nkt_eff = nkt;
  if constexpr (KLIMIT) { int c = (bm+1)*4; if (c < nkt_eff) nkt_eff = c; }

  const int tid = threadIdx.x;
  const int wid = tid >> 6, lane = tid & 63;
  const int wr = wid >> 2, wc = wid & 3;
  const int l15 = lane & 15, g = lane >> 4;

  const bf16* Ab = A + (long)bz*sAb + (long)bm*256*lda;
  const bf16* Bb = B + (long)bz*sBb + (long)bn*256*ldb;

  // staging: per half-tile (128 rows x 64 cols bf16 = 16KB), 2 loads/thread.
  // source col pre-swizzled (inverse of read swizzle, involution on byte bit5^bit9)
  const int colsw = ((tid & 7) * 8) ^ ((tid & 32) ? 16 : 0);
  const bf16* A0 = Ab + (long)(tid >> 3)*lda + colsw;
  const bf16* B0 = Bb + (long)(tid >> 3)*ldb + colsw;

  // stage half-tile: ab=0 A, ab=1 B; h=0/1; slot=0/1; tile t
  auto stage = [&](int ab, int t, int h, int slot) {
    char* dst = smem + slot*65536 + ab*32768 + h*16384 + wid*1024;
    const bf16* s0 = (ab ? B0 : A0) + (long)(h*128)*(ab ? ldb : lda) + (long)t*64;
    load_lds16(s0, dst);
    load_lds16(s0 + 64*(ab ? ldb : lda), dst + 8192);
  };

  const char* sm = smem;
  auto aLoad = [&](int slot, int m, int kk) -> bf16x8 {
    int row = m*16 + l15;
    int b = row*128 + kk*64 + g*16;
    b ^= (row & 4) << 3;
    return *(const bf16x8*)(sm + slot*65536 + wr*16384 + b);
  };
  auto bLoad = [&](int slot, int n, int kk) -> bf16x8 {
    int row = (wc & 1)*64 + n*16 + l15;
    int b = row*128 + kk*64 + g*16;
    b ^= (row & 4) << 3;
    return *(const bf16x8*)(sm + slot*65536 + 32768 + (wc >> 1)*16384 + b);
  };

  f32x4 acc[8][4] = {};

  // prologue: tile0 fully into slot0, tile1 half A.h0 into slot1
  stage(0, 0, 0, 0);
  stage(0, 0, 1, 0);
  stage(1, 0, 0, 0);
  stage(1, 0, 1, 0);
  stage(0, 1, 0, 1);
  asm volatile("s_waitcnt vmcnt(2)" ::: "memory");
  bar();

  const int niter = nkt_eff >> 1;
  for (int it = 0; it < niter; ++it) {
    const int t0 = 2*it, t1 = 2*it + 1;
    const int tn0 = (t0+2 < nkt_eff) ? t0+2 : nkt_eff-1;
    const int tn1 = (t1+2 < nkt_eff) ? t1+2 : nkt_eff-1;
    bf16x8 a0[4][2], a1[4][2], b0[2][2], b1[2][2];

    // -- P1: read A[0..3],B[0..1] slot0; stage t1 A.h1; mfma q(0,0)
    #pragma unroll
    for (int m=0;m<4;++m) { a0[m][0]=aLoad(0,m,0); a0[m][1]=aLoad(0,m,1); }
    #pragma unroll
    for (int n=0;n<2;++n) { b0[n][0]=bLoad(0,n,0); b0[n][1]=bLoad(0,n,1); }
    stage(0, t1, 1, 1);
    bar();
    __builtin_amdgcn_s_setprio(1);
    #pragma unroll
    for (int m=0;m<4;++m)
      #pragma unroll
      for (int n=0;n<2;++n) {
        acc[m][n] = __builtin_amdgcn_mfma_f32_16x16x32_bf16(a0[m][0], b0[n][0], acc[m][n],0,0,0);
        acc[m][n] = __builtin_amdgcn_mfma_f32_16x16x32_bf16(a0[m][1], b0[n][1], acc[m][n],0,0,0);
      }
    __builtin_amdgcn_s_setprio(0);
    bar();

    // -- P2: read B[2..3] slot0; stage t1 B.h0; mfma q(0,1)
    #pragma unroll
    for (int n=0;n<2;++n) { b1[n][0]=bLoad(0,n+2,0); b1[n][1]=bLoad(0,n+2,1); }
    stage(1, t1, 0, 1);
    bar();
    __builtin_amdgcn_s_setprio(1);
    #pragma unroll
    for (int m=0;m<4;++m)
      #pragma unroll
      for (int n=0;n<2;++n) {
        acc[m][n+2] = __builtin_amdgcn_mfma_f32_16x16x32_bf16(a0[m][0], b1[n][0], acc[m][n+2],0,0,0);
        acc[m][n+2] = __builtin_amdgcn_mfma_f32_16x16x32_bf16(a0[m][1], b1[n][1], acc[m][n+2],0,0,0);
      }
    __builtin_amdgcn_s_setprio(0);
    bar();

    // -- P3: read A[4..7] slot0; stage t1 B.h1; mfma q(1,1)
    #pragma unroll
    for (int m=0;m<4;++m) { a1[m][0]=aLoad(0,m+4,0); a1[m][1]=aLoad(0,m+4,1); }
    stage(1, t1, 1, 1);
    bar();
    __builtin_amdgcn_s_setprio(1);
    #pragma unroll
    for (int m=0;m<4;++m)
      #pragma unroll
      for (int n=0;n<2;++n) {
        acc[m+4][n+2] = __builtin_amdgcn_mfma_f32_16x16x32_bf16(a1[m][0], b1[n][0], acc[m+4][n+2],0,0,0);
        acc[m+4][n+2] = __builtin_amdgcn_mfma_f32_16x16x32_bf16(a1[m][1], b1[n][1], acc[m+4][n+2],0,0,0);
      }
    __builtin_amdgcn_s_setprio(0);
    bar();

    // -- P4: stage tn0 A.h0 -> slot0; vmcnt(2) => t1 fully resident; mfma q(1,0)
    stage(0, tn0, 0, 0);
    asm volatile("s_waitcnt vmcnt(2)" ::: "memory");
    bar();
    __builtin_amdgcn_s_setprio(1);
    #pragma unroll
    for (int m=0;m<4;++m)
      #pragma unroll
      for (int n=0;n<2;++n) {
        acc[m+4][n] = __builtin_amdgcn_mfma_f32_16x16x32_bf16(a1[m][0], b0[n][0], acc[m+4][n],0,0,0);
        acc[m+4][n] = __builtin_amdgcn_mfma_f32_16x16x32_bf16(a1[m][1], b0[n][1], acc[m+4][n],0,0,0);
      }
    __builtin_amdgcn_s_setprio(0);
    bar();

    // -- P5: read A[0..3],B[0..1] slot1; stage tn0 A.h1; mfma q'(0,0)
    #pragma unroll
    for (int m=0;m<4;++m) { a0[m][0]=aLoad(1,m,0); a0[m][1]=aLoad(1,m,1); }
    #pragma unroll
    for (int n=0;n<2;++n) { b0[n][0]=bLoad(1,n,0); b0[n][1]=bLoad(1,n,1); }
    stage(0, tn0, 1, 0);
    bar();
    __builtin_amdgcn_s_setprio(1);
    #pragma unroll
    for (int m=0;m<4;++m)
      #pragma unroll
      for (int n=0;n<2;++n) {
        acc[m][n] = __builtin_amdgcn_mfma_f32_16x16x32_bf16(a0[m][0], b0[n][0], acc[m][n],0,0,0);
        acc[m][n] = __builtin_amdgcn_mfma_f32_16x16x32_bf16(a0[m][1], b0[n][1], acc[m][n],0,0,0);
      }
    __builtin_amdgcn_s_setprio(0);
    bar();

    // -- P6: read B[2..3] slot1; stage tn0 B.h0; mfma q'(0,1)
    #pragma unroll
    for (int n=0;n<2;++n) { b1[n][0]=bLoad(1,n+2,0); b1[n][1]=bLoad(1,n+2,1); }
    stage(1, tn0, 0, 0);
    bar();
    __builtin_amdgcn_s_setprio(1);
    #pragma unroll
    for (int m=0;m<4;++m)
      #pragma unroll
      for (int n=0;n<2;++n) {
        acc[m][n+2] = __builtin_amdgcn_mfma_f32_16x16x32_bf16(a0[m][0], b1[n][0], acc[m][n+2],0,0,0);
        acc[m][n+2] = __builtin_amdgcn_mfma_f32_16x16x32_bf16(a0[m][1], b1[n][1], acc[m][n+2],0,0,0);
      }
    __builtin_amdgcn_s_setprio(0);
    bar();

    // -- P7: read A[4..7] slot1; stage tn0 B.h1; mfma q'(1,1)
    #pragma unroll
    for (int m=0;m<4;++m) { a1[m][0]=aLoad(1,m+4,0); a1[m][1]=aLoad(1,m+4,1); }
    stage(1, tn0, 1, 0);
    bar();
    __builtin_amdgcn_s_setprio(1);
    #pragma unroll
    for (int m=0;m<4;++m)
      #pragma unroll
      for (int n=0;n<2;++n) {
        acc[m+4][n+2] = __builtin_amdgcn_mfma_f32_16x16x32_bf16(a1[m][0], b1[n][0], acc[m+4][n+2],0,0,0);
        acc[m+4][n+2] = __builtin_amdgcn_mfma_f32_16x16x32_bf16(a1[m][1], b1[n][1], acc[m+4][n+2],0,0,0);
      }
    __builtin_amdgcn_s_setprio(0);
    bar();

    // -- P8: stage tn1 A.h0 -> slot1; vmcnt(2) => tn0 (next slot0) resident; mfma q'(1,0)
    stage(0, tn1, 0, 1);
    asm volatile("s_waitcnt vmcnt(2)" ::: "memory");
    bar();
    __builtin_amdgcn_s_setprio(1);
    #pragma unroll
    for (int m=0;m<4;++m)
      #pragma unroll
      for (int n=0;n<2;++n) {
        acc[m+4][n] = __builtin_amdgcn_mfma_f32_16x16x32_bf16(a1[m][0], b0[n][0], acc[m+4][n],0,0,0);
        acc[m+4][n] = __builtin_amdgcn_mfma_f32_16x16x32_bf16(a1[m][1], b0[n][1], acc[m+4][n],0,0,0);
      }
    __builtin_amdgcn_s_setprio(0);
    bar();
  }

  const long rowbase = (long)bm*256 + wr*128;
  const long colbase = (long)bn*256 + wc*64;

  if constexpr (EPI == EPI_LMHEAD) {
    #pragma unroll
    for (int m=0;m<8;++m)
      #pragma unroll
      for (int n=0;n<4;++n) {
        long c = colbase + n*16 + l15;
        float bv = bias[c];
        #pragma unroll
        for (int q_=0;q_<4;++q_) {
          acc[m][n][q_] += bv;
          long rr = rowbase + m*16 + g*4 + q_;
          outf[rr*ldo + c] = acc[m][n][q_];
        }
      }
    __syncthreads();   // drains vmcnt too -> safe smem reuse
    float* redm = (float*)smem;       // [4][256]
    float* reds = redm + 1024;
    #pragma unroll
    for (int m=0;m<8;++m)
      #pragma unroll
      for (int q_=0;q_<4;++q_) {
        float mx = fmaxf(fmaxf(acc[m][0][q_], acc[m][1][q_]),
                         fmaxf(acc[m][2][q_], acc[m][3][q_]));
        #pragma unroll
        for (int msk=8;msk>=1;msk>>=1) mx = fmaxf(mx, __shfl_xor(mx, msk));
        float se = 0.f;
        #pragma unroll
        for (int n=0;n<4;++n) se += __expf(acc[m][n][q_] - mx);
        #pragma unroll
        for (int msk=8;msk>=1;msk>>=1) se += __shfl_xor(se, msk);
        if (l15 == 0) {
          int rloc = wr*128 + m*16 + g*4 + q_;
          redm[wc*256 + rloc] = mx;
          reds[wc*256 + rloc] = se;
        }
      }
    __syncthreads();
    if (tid < 256) {
      float m0=redm[tid], m1=redm[256+tid], m2=redm[512+tid], m3=redm[768+tid];
      float M = fmaxf(fmaxf(m0,m1), fmaxf(m2,m3));
      float Sv = reds[tid]*__expf(m0-M) + reds[256+tid]*__expf(m1-M)
               + reds[512+tid]*__expf(m2-M) + reds[768+tid]*__expf(m3-M);
      long row = (long)bm*256 + tid;
      pmax[row*NCHUNK + bn] = M;
      psum[row*NCHUNK + bn] = Sv;
    }
  } else {
    #pragma unroll
    for (int m=0;m<8;++m)
      #pragma unroll
      for (int n=0;n<4;++n) {
        long c = colbase + n*16 + l15;
        #pragma unroll
        for (int q_=0;q_<4;++q_) {
          long rr = rowbase + m*16 + g*4 + q_;
          float v = acc[m][n][q_];
          if constexpr (EPI == EPI_F32) {
            outf[(long)bz*sOb + rr*ldo + c] = v;
          } else if constexpr (EPI == EPI_BF16) {
            outb[(long)bz*sOb + rr*ldo + c] = (bf16)v;
          } else if constexpr (EPI == EPI_BIAS_RELU_BF16) {
            outb[rr*ldo + c] = (bf16)fmaxf(v + bias[c], 0.f);
          } else if constexpr (EPI == EPI_BIAS_RES_BF16) {
            outb[rr*ldo + c] = (bf16)(v + bias[c] + res[rr*ldr + c]);
          } else if constexpr (EPI == EPI_RES_F32) {
            outf[(long)bz*sOb + rr*ldo + c] = v + res[(long)bz*sRb + rr*ldr + c];
          }
        }
      }
  }
}

// ---------------- loss pass 1 ----------------
__global__ __launch_bounds__(256)
void loss1_kernel(const float* __restrict__ pmax, const float* __restrict__ psum,
                  const float* __restrict__ logits, const int* __restrict__ targets,
                  float* __restrict__ rowloss) {
  int row = blockIdx.x;
  int tid = threadIdx.x;
  int lane = tid & 63, wv = tid >> 6;
  float cm = (tid < NCHUNK) ? pmax[(long)row*NCHUNK + tid] : -1e30f;
  float cs = (tid < NCHUNK) ? psum[(long)row*NCHUNK + tid] : 0.f;
  float mx = cm;
  #pragma unroll
  for (int m=32;m>=1;m>>=1) mx = fmaxf(mx, __shfl_xor(mx, m));
  __shared__ float rm[4];
  if (lane == 0) rm[wv] = mx;
  __syncthreads();
  float M = fmaxf(fmaxf(rm[0],rm[1]), fmaxf(rm[2],rm[3]));
  float sc = cs * __expf(cm - M);
  #pragma unroll
  for (int m=32;m>=1;m>>=1) sc += __shfl_xor(sc, m);
  __shared__ float rs_[4];
  if (lane == 0) rs_[wv] = sc;
  __syncthreads();
  if (tid == 0) {
    float Sv = rs_[0]+rs_[1]+rs_[2]+rs_[3];
    float lse = M + logf(Sv);
    int tgt = targets[row];
    float lg = logits[(long)row*NV + tgt];
    rowloss[row] = lse - lg;
  }
}

// ---------------- loss pass 2 ----------------
__global__ __launch_bounds__(256)
void loss2_kernel(const float* __restrict__ rowloss, float* __restrict__ out) {
  int tid = threadIdx.x;
  float s = 0.f;
  for (int i = tid; i < NROWS; i += 256) s += rowloss[i];
  #pragma unroll
  for (int m=32;m>=1;m>>=1) s += __shfl_xor(s, m);
  __shared__ float rs_[4];
  if ((tid & 63) == 0) rs_[tid>>6] = s;
  __syncthreads();
  if (tid == 0) out[0] = (rs_[0]+rs_[1]+rs_[2]+rs_[3]) * (1.f/NROWS);
}

// ---------------- launcher ----------------
extern "C" void kernel_launch(void* const* d_in, const int* in_sizes, int n_in,
                              void* d_out, int out_size, void* d_ws, size_t ws_size,
                              hipStream_t stream) {
  const int*   idx  = (const int*)d_in[0];
  const int*   tgt  = (const int*)d_in[1];
  const float* tok  = (const float*)d_in[2];
  const float* pos  = (const float*)d_in[3];
  const float* Wk   = (const float*)d_in[4];
  const float* Wq   = (const float*)d_in[5];
  const float* Wv   = (const float*)d_in[6];
  const float* W1   = (const float*)d_in[7];
  const float* b1   = (const float*)d_in[8];
  const float* W2   = (const float*)d_in[9];
  const float* b2   = (const float*)d_in[10];
  const float* g1   = (const float*)d_in[11];
  const float* be1  = (const float*)d_in[12];
  const float* g2   = (const float*)d_in[13];
  const float* be2  = (const float*)d_in[14];
  const float* Wlm  = (const float*)d_in[15];
  const float* blm  = (const float*)d_in[16];

  float* logits = (float*)d_out;
  float* loss   = logits + (long)NROWS*NV;

  char* w = (char*)d_ws;
  auto alloc = [&](size_t bytes) -> char* {
    char* p = w; w += (bytes + 255) & ~(size_t)255; return p;
  };
  bf16* wqkvb = (bf16*)alloc((size_t)3*NC*NC*2);   // [1536][512]: Wq,Wk,Wv stacked
  bf16* w1b   = (bf16*)alloc((size_t)4*NC*NC*2);
  bf16* w2b   = (bf16*)alloc((size_t)4*NC*NC*2);
  bf16* wlmb  = (bf16*)alloc((size_t)NV*NC*2);
  float* x0   = (float*)alloc((size_t)NROWS*NC*4);
  bf16* h1b   = (bf16*)alloc((size_t)NROWS*NC*2);
  bf16* qkvb  = (bf16*)alloc((size_t)NROWS*3*NC*2); // [8192][1536]
  bf16* vtb   = (bf16*)alloc((size_t)NROWS*NC*2);
  float* Sb   = (float*)alloc((size_t)NB*NT*NT*4);  // P (bf16) aliased inside
  float* x1   = (float*)alloc((size_t)NROWS*NC*4);
  bf16* h2b   = (bf16*)alloc((size_t)NROWS*NC*2);
  bf16* ffb   = (bf16*)alloc((size_t)NROWS*4*NC*2);
  bf16* x2b   = (bf16*)alloc((size_t)NROWS*NC*2);
  float* pmax = (float*)alloc((size_t)NROWS*NCHUNK*4);
  float* psum = (float*)alloc((size_t)NROWS*NCHUNK*4);
  float* rowloss = (float*)alloc((size_t)NROWS*4);

  hipFuncSetAttribute((const void*)gemm256<EPI_BF16,false,false,false>,
                      hipFuncAttributeMaxDynamicSharedMemorySize, SMEM_B);
  hipFuncSetAttribute((const void*)gemm256<EPI_F32,true,false,false>,
                      hipFuncAttributeMaxDynamicSharedMemorySize, SMEM_B);
  hipFuncSetAttribute((const void*)gemm256<EPI_RES_F32,false,true,false>,
                      hipFuncAttributeMaxDynamicSharedMemorySize, SMEM_B);
  hipFuncSetAttribute((const void*)gemm256<EPI_BIAS_RELU_BF16,false,false,false>,
                      hipFuncAttributeMaxDynamicSharedMemorySize, SMEM_B);
  hipFuncSetAttribute((const void*)gemm256<EPI_BIAS_RES_BF16,false,false,false>,
                      hipFuncAttributeMaxDynamicSharedMemorySize, SMEM_B);
  hipFuncSetAttribute((const void*)gemm256<EPI_LMHEAD,false,false,true>,
                      hipFuncAttributeMaxDynamicSharedMemorySize, SMEM_B);

  auto cvt = [&](const float* in, bf16* out, long n) {
    int n8 = (int)(n/8);
    int blocks = (n8 + 255)/256; if (blocks > 2048) blocks = 2048;
    cvt_kernel<<<blocks, 256, 0, stream>>>(in, out, n8);
  };
  cvt(Wq, wqkvb, (long)NC*NC);
  cvt(Wk, wqkvb + (long)NC*NC, (long)NC*NC);
  cvt(Wv, wqkvb + (long)2*NC*NC, (long)NC*NC);
  cvt(W1, w1b, (long)4*NC*NC);
  cvt(W2, w2b, (long)4*NC*NC);
  cvt(Wlm, wlmb, (long)NV*NC);

  embed_kernel<<<NROWS, 64, 0, stream>>>(idx, tok, pos, x0);
  ln_kernel<<<NROWS, 64, 0, stream>>>(x0, g1, be1, h1b);

  // fused QKV: qkv[8192][1536] = h1 * Wqkv^T
  gemm256<EPI_BF16><<<dim3(6,32,1), 512, SMEM_B, stream>>>(
      h1b, wqkvb, 8, NC, NC, 0, 0, nullptr, qkvb, 3*NC, 0,
      nullptr, nullptr, 0, 0, nullptr, nullptr);

  transpose_kernel<<<dim3(NT/64, NC/64, NB), 256, 0, stream>>>(qkvb + 2*NC, 3*NC, vtb);

  // S = q k^T (per batch), causal block skip
  gemm256<EPI_F32,true><<<dim3(8,8,NB), 512, SMEM_B, stream>>>(
      qkvb, qkvb + NC, 8, 3*NC, 3*NC, (long)NT*3*NC, (long)NT*3*NC,
      Sb, nullptr, NT, (long)NT*NT,
      nullptr, nullptr, 0, 0, nullptr, nullptr);

  softmax_kernel<<<NROWS, 256, 0, stream>>>(Sb);

  // x1 = x0 + P vT^T (per batch), causal K-limit
  gemm256<EPI_RES_F32,false,true><<<dim3(2,8,NB), 512, SMEM_B, stream>>>(
      (const bf16*)Sb, vtb, 32, 2*NT, NT, (long)NT*2*NT, (long)NC*NT,
      x1, nullptr, NC, (long)NT*NC,
      nullptr, x0, NC, (long)NT*NC, nullptr, nullptr);

  ln_kernel<<<NROWS, 64, 0, stream>>>(x1, g2, be2, h2b);

  // ff = relu(h2 W1^T + b1)
  gemm256<EPI_BIAS_RELU_BF16><<<dim3(8,32,1), 512, SMEM_B, stream>>>(
      h2b, w1b, 8, NC, NC, 0, 0, nullptr, ffb, 4*NC, 0,
      b1, nullptr, 0, 0, nullptr, nullptr);

  // x2 = x1 + ff W2^T + b2
  gemm256<EPI_BIAS_RES_BF16><<<dim3(2,32,1), 512, SMEM_B, stream>>>(
      ffb, w2b, 32, 4*NC, 4*NC, 0, 0, nullptr, x2b, NC, 0,
      b2, x1, NC, 0, nullptr, nullptr);

  // logits + per-256-col-chunk (max,sumexp) partials
  gemm256<EPI_LMHEAD,false,false,true><<<dim3(NCHUNK,32,1), 512, SMEM_B, stream>>>(
      x2b, wlmb, 8, NC, NC, 0, 0, logits, nullptr, NV, 0,
      blm, nullptr, 0, 0, pmax, psum);

  loss1_kernel<<<NROWS, 256, 0, stream>>>(pmax, psum, logits, tgt, rowloss);
  loss2_kernel<<<1, 256, 0, stream>>>(rowloss, loss);
}

// Round 3
// 787.048 us; speedup vs baseline: 1.1409x; 1.1409x over previous
//
#include <hip/hip_runtime.h>

typedef __bf16 bf16;
typedef __bf16 bf16x8 __attribute__((ext_vector_type(8)));
typedef float  f32x4  __attribute__((ext_vector_type(4)));

#define NB 4
#define NT 2048
#define NC 512
#define NV 32000
#define NROWS (NB*NT)          // 8192
#define NCHUNK (NV/256)        // 125
#define LNEPS 1e-5f
#define SMEM_B 131072

static __device__ __forceinline__ void load_lds16(const bf16* g, char* l) {
  __builtin_amdgcn_global_load_lds(
      (const __attribute__((address_space(1))) void*)g,
      (__attribute__((address_space(3))) void*)l, 16, 0, 0);
}

static __device__ __forceinline__ void bar() {
  asm volatile("" ::: "memory");
  __builtin_amdgcn_s_barrier();
  asm volatile("" ::: "memory");
}

// ---------------- f32 -> bf16 convert (vectorized x8) ----------------
__global__ __launch_bounds__(256)
void cvt_kernel(const float* __restrict__ in, bf16* __restrict__ out, int n8) {
  long i = (long)blockIdx.x * 256 + threadIdx.x;
  long stride = (long)gridDim.x * 256;
  for (; i < n8; i += stride) {
    const float* p = in + i * 8;
    f32x4 a = *(const f32x4*)p;
    f32x4 b = *(const f32x4*)(p + 4);
    bf16x8 o;
    o[0]=(bf16)a.x; o[1]=(bf16)a.y; o[2]=(bf16)a.z; o[3]=(bf16)a.w;
    o[4]=(bf16)b.x; o[5]=(bf16)b.y; o[6]=(bf16)b.z; o[7]=(bf16)b.w;
    *(bf16x8*)(out + i*8) = o;
  }
}

// ---------------- embedding ----------------
__global__ __launch_bounds__(64)
void embed_kernel(const int* __restrict__ idx, const float* __restrict__ tok,
                  const float* __restrict__ pos, float* __restrict__ x0) {
  int row = blockIdx.x;
  int t = row & (NT-1);
  int id = idx[row];
  int lane = threadIdx.x;
  const float* tr = tok + (long)id*NC + lane*8;
  const float* pr = pos + (long)t*NC + lane*8;
  f32x4 a0 = *(const f32x4*)tr, a1 = *(const f32x4*)(tr+4);
  f32x4 p0 = *(const f32x4*)pr, p1 = *(const f32x4*)(pr+4);
  f32x4 r0 = a0 + p0, r1 = a1 + p1;
  float* o = x0 + (long)row*NC + lane*8;
  *(f32x4*)o = r0; *(f32x4*)(o+4) = r1;
}

// ---------------- layernorm: one wave per row of 512 ----------------
__global__ __launch_bounds__(64)
void ln_kernel(const float* __restrict__ x, const float* __restrict__ gw,
               const float* __restrict__ bw, bf16* __restrict__ out) {
  int row = blockIdx.x;
  int lane = threadIdx.x;
  const float* xr = x + (long)row*NC + lane*8;
  f32x4 a = *(const f32x4*)xr;
  f32x4 b = *(const f32x4*)(xr+4);
  float v[8] = {a.x,a.y,a.z,a.w,b.x,b.y,b.z,b.w};
  float s = 0.f;
  #pragma unroll
  for (int j=0;j<8;++j) s += v[j];
  #pragma unroll
  for (int m=32;m>=1;m>>=1) s += __shfl_xor(s, m);
  float mu = s * (1.f/NC);
  float sq = 0.f;
  #pragma unroll
  for (int j=0;j<8;++j) { v[j] -= mu; sq += v[j]*v[j]; }
  #pragma unroll
  for (int m=32;m>=1;m>>=1) sq += __shfl_xor(sq, m);
  float rs = rsqrtf(sq * (1.f/NC) + LNEPS);
  const float* gp = gw + lane*8;
  const float* bp = bw + lane*8;
  f32x4 g0 = *(const f32x4*)gp, g1 = *(const f32x4*)(gp+4);
  f32x4 b0 = *(const f32x4*)bp, b1 = *(const f32x4*)(bp+4);
  float gg[8] = {g0.x,g0.y,g0.z,g0.w,g1.x,g1.y,g1.z,g1.w};
  float bb[8] = {b0.x,b0.y,b0.z,b0.w,b1.x,b1.y,b1.z,b1.w};
  bf16x8 o;
  #pragma unroll
  for (int j=0;j<8;++j) o[j] = (bf16)(v[j]*rs*gg[j] + bb[j]);
  *(bf16x8*)(out + (long)row*NC + lane*8) = o;
}

// ---------------- transpose v[b][t][c] (stride ldv) -> vt[b][c][t] ----------------
__global__ __launch_bounds__(256)
void transpose_kernel(const bf16* __restrict__ v, long ldv, bf16* __restrict__ vt) {
  __shared__ bf16 tile[64][66];
  int b = blockIdx.z;
  int t0 = blockIdx.x*64, c0 = blockIdx.y*64;
  int tid = threadIdx.x;
  int r = tid >> 2, ch = (tid & 3) * 16;
  const bf16* src = v + ((long)b*NT + t0 + r)*ldv + c0 + ch;
  #pragma unroll
  for (int i=0;i<16;++i) tile[r][ch+i] = src[i];
  __syncthreads();
  bf16x8 o0, o1;
  #pragma unroll
  for (int i=0;i<8;++i) o0[i] = tile[ch+i][r];
  #pragma unroll
  for (int i=0;i<8;++i) o1[i] = tile[ch+8+i][r];
  bf16* dst = vt + ((long)b*NC + c0 + r)*NT + t0 + ch;
  *(bf16x8*)dst = o0;
  *(bf16x8*)(dst+8) = o1;
}

// ---------------- causal softmax row: S f32 -> P bf16 (aliased into S) ----------------
__global__ __launch_bounds__(256)
void softmax_kernel(float* __restrict__ S) {
  const int row = blockIdx.x;
  const int t = row & (NT-1);
  const int tid = threadIdx.x;
  float* sr = S + (long)row*NT;
  bf16* pr = (bf16*)S + (long)row*(2*NT);
  const float scale = 0.044194173824159216f;
  f32x4 v0 = *(const f32x4*)(sr + tid*8);
  f32x4 v1 = *(const f32x4*)(sr + tid*8 + 4);
  float v[8] = {v0.x,v0.y,v0.z,v0.w,v1.x,v1.y,v1.z,v1.w};
  int cb = tid*8;
  float mx = -1e30f;
  #pragma unroll
  for (int j=0;j<8;++j) {
    v[j] = (cb + j <= t) ? v[j]*scale : -1e30f;
    mx = fmaxf(mx, v[j]);
  }
  __shared__ float redm[4];
  #pragma unroll
  for (int m=32;m>=1;m>>=1) mx = fmaxf(mx, __shfl_xor(mx, m));
  if ((tid & 63) == 0) redm[tid>>6] = mx;
  __syncthreads();
  mx = fmaxf(fmaxf(redm[0],redm[1]), fmaxf(redm[2],redm[3]));
  float e[8]; float s = 0.f;
  #pragma unroll
  for (int j=0;j<8;++j) { e[j] = (cb + j <= t) ? __expf(v[j]-mx) : 0.f; s += e[j]; }
  __shared__ float reds[4];
  #pragma unroll
  for (int m=32;m>=1;m>>=1) s += __shfl_xor(s, m);
  if ((tid & 63) == 0) reds[tid>>6] = s;
  __syncthreads();
  s = reds[0]+reds[1]+reds[2]+reds[3];
  float inv = 1.f/s;
  bf16x8 o;
  #pragma unroll
  for (int j=0;j<8;++j) o[j] = (bf16)(e[j]*inv);
  *(bf16x8*)(pr + cb) = o;
}

// ======== 256x256-tile 8-phase GEMM: out[M,N] = A[M,K] * B[N,K]^T ========
// 512 threads = 8 waves (2 wr x 4 wc); per-wave 128x64 out; BK=64; LDS 128KB.
// Swizzle: lds[r][bc] holds global[r][bc ^ ((r&7)<<4)] (byte addrs) -> each
// 16-lane quarter-wave ds_read_b128 group covers all 8 16B slots, 2 lanes each
// (conflict-free). Source pre-swizzled, dest linear (rule 21).
enum { EPI_F32=0, EPI_BF16=1, EPI_BIAS_RELU_BF16=2, EPI_BIAS_RES_BF16=3, EPI_RES_F32=4, EPI_LMHEAD=5 };

template<int EPI, bool CAUSAL=false, bool KLIMIT=false, bool SWZ=false>
__global__ __launch_bounds__(512,2)
void gemm256(const bf16* __restrict__ A, const bf16* __restrict__ B, int nkt,
             long lda, long ldb, long sAb, long sBb,
             float* __restrict__ outf, bf16* __restrict__ outb, long ldo, long sOb,
             const float* __restrict__ bias,
             const float* __restrict__ res, long ldr, long sRb,
             float* __restrict__ pmax, float* __restrict__ psum) {
  extern __shared__ char smem[];
  int bn = blockIdx.x, bm = blockIdx.y;
  const int bz = blockIdx.z;
  if constexpr (SWZ) {
    int gx = gridDim.x, nwg = gx * gridDim.y;
    int flat = bm * gx + bn;
    int q = nwg >> 3, r = nwg & 7;
    int xcd = flat & 7, pos = flat >> 3;
    int wgid = (xcd < r ? xcd*(q+1) : r*(q+1) + (xcd-r)*q) + pos;
    bn = wgid % gx; bm = wgid / gx;
  }
  if constexpr (CAUSAL) { if (bn > bm) return; }
  int nkt_eff = nkt;
  if constexpr (KLIMIT) { int c = (bm+1)*4; if (c < nkt_eff) nkt_eff = c; }

  const int tid = threadIdx.x;
  const int wid = tid >> 6, lane = tid & 63;
  const int wr = wid >> 2, wc = wid & 3;
  const int l15 = lane & 15, g = lane >> 4;

  const bf16* Ab = A + (long)bz*sAb + (long)bm*256*lda;
  const bf16* Bb = B + (long)bz*sBb + (long)bn*256*ldb;

  // source pre-swizzle: thread covers lds row (tid>>3), byte col (tid&7)*16;
  // must fetch global byte col ((tid&7)*16) ^ (((tid>>3)&7)<<4)
  const int colsw = 8 * ((tid & 7) ^ ((tid >> 3) & 7));
  const bf16* A0 = Ab + (long)(tid >> 3)*lda + colsw;
  const bf16* B0 = Bb + (long)(tid >> 3)*ldb + colsw;

  // stage half-tile: ab=0 A, ab=1 B; h=0/1; slot=0/1; tile t
  auto stage = [&](int ab, int t, int h, int slot) {
    char* dst = smem + slot*65536 + ab*32768 + h*16384 + wid*1024;
    const bf16* s0 = (ab ? B0 : A0) + (long)(h*128)*(ab ? ldb : lda) + (long)t*64;
    load_lds16(s0, dst);
    load_lds16(s0 + 64*(ab ? ldb : lda), dst + 8192);
  };

  const char* sm = smem;
  auto aLoad = [&](int slot, int m, int kk) -> bf16x8 {
    int row = m*16 + l15;
    int b = row*128 + ((kk*64 + g*16) ^ ((row & 7) << 4));
    return *(const bf16x8*)(sm + slot*65536 + wr*16384 + b);
  };
  auto bLoad = [&](int slot, int n, int kk) -> bf16x8 {
    int row = (wc & 1)*64 + n*16 + l15;
    int b = row*128 + ((kk*64 + g*16) ^ ((row & 7) << 4));
    return *(const bf16x8*)(sm + slot*65536 + 32768 + (wc >> 1)*16384 + b);
  };

  f32x4 acc[8][4] = {};

  // prologue: tile0 fully into slot0, tile1 half A.h0 into slot1
  stage(0, 0, 0, 0);
  stage(0, 0, 1, 0);
  stage(1, 0, 0, 0);
  stage(1, 0, 1, 0);
  stage(0, 1, 0, 1);
  asm volatile("s_waitcnt vmcnt(2)" ::: "memory");
  bar();

  const int niter = nkt_eff >> 1;
  for (int it = 0; it < niter; ++it) {
    const int t0 = 2*it, t1 = 2*it + 1;
    const int tn0 = (t0+2 < nkt_eff) ? t0+2 : nkt_eff-1;
    const int tn1 = (t1+2 < nkt_eff) ? t1+2 : nkt_eff-1;
    bf16x8 a0[4][2], a1[4][2], b0[2][2], b1[2][2];

    // -- P1: read A[0..3],B[0..1] slot0; stage t1 A.h1; mfma q(0,0)
    #pragma unroll
    for (int m=0;m<4;++m) { a0[m][0]=aLoad(0,m,0); a0[m][1]=aLoad(0,m,1); }
    #pragma unroll
    for (int n=0;n<2;++n) { b0[n][0]=bLoad(0,n,0); b0[n][1]=bLoad(0,n,1); }
    stage(0, t1, 1, 1);
    bar();
    __builtin_amdgcn_s_setprio(1);
    #pragma unroll
    for (int m=0;m<4;++m)
      #pragma unroll
      for (int n=0;n<2;++n) {
        acc[m][n] = __builtin_amdgcn_mfma_f32_16x16x32_bf16(a0[m][0], b0[n][0], acc[m][n],0,0,0);
        acc[m][n] = __builtin_amdgcn_mfma_f32_16x16x32_bf16(a0[m][1], b0[n][1], acc[m][n],0,0,0);
      }
    __builtin_amdgcn_s_setprio(0);
    bar();

    // -- P2: read B[2..3] slot0; stage t1 B.h0; mfma q(0,1)
    #pragma unroll
    for (int n=0;n<2;++n) { b1[n][0]=bLoad(0,n+2,0); b1[n][1]=bLoad(0,n+2,1); }
    stage(1, t1, 0, 1);
    bar();
    __builtin_amdgcn_s_setprio(1);
    #pragma unroll
    for (int m=0;m<4;++m)
      #pragma unroll
      for (int n=0;n<2;++n) {
        acc[m][n+2] = __builtin_amdgcn_mfma_f32_16x16x32_bf16(a0[m][0], b1[n][0], acc[m][n+2],0,0,0);
        acc[m][n+2] = __builtin_amdgcn_mfma_f32_16x16x32_bf16(a0[m][1], b1[n][1], acc[m][n+2],0,0,0);
      }
    __builtin_amdgcn_s_setprio(0);
    bar();

    // -- P3: read A[4..7] slot0; stage t1 B.h1; mfma q(1,1)
    #pragma unroll
    for (int m=0;m<4;++m) { a1[m][0]=aLoad(0,m+4,0); a1[m][1]=aLoad(0,m+4,1); }
    stage(1, t1, 1, 1);
    bar();
    __builtin_amdgcn_s_setprio(1);
    #pragma unroll
    for (int m=0;m<4;++m)
      #pragma unroll
      for (int n=0;n<2;++n) {
        acc[m+4][n+2] = __builtin_amdgcn_mfma_f32_16x16x32_bf16(a1[m][0], b1[n][0], acc[m+4][n+2],0,0,0);
        acc[m+4][n+2] = __builtin_amdgcn_mfma_f32_16x16x32_bf16(a1[m][1], b1[n][1], acc[m+4][n+2],0,0,0);
      }
    __builtin_amdgcn_s_setprio(0);
    bar();

    // -- P4: stage tn0 A.h0 -> slot0; vmcnt(2) => t1 fully resident; mfma q(1,0)
    stage(0, tn0, 0, 0);
    asm volatile("s_waitcnt vmcnt(2)" ::: "memory");
    bar();
    __builtin_amdgcn_s_setprio(1);
    #pragma unroll
    for (int m=0;m<4;++m)
      #pragma unroll
      for (int n=0;n<2;++n) {
        acc[m+4][n] = __builtin_amdgcn_mfma_f32_16x16x32_bf16(a1[m][0], b0[n][0], acc[m+4][n],0,0,0);
        acc[m+4][n] = __builtin_amdgcn_mfma_f32_16x16x32_bf16(a1[m][1], b0[n][1], acc[m+4][n],0,0,0);
      }
    __builtin_amdgcn_s_setprio(0);
    bar();

    // -- P5: read A[0..3],B[0..1] slot1; stage tn0 A.h1; mfma q'(0,0)
    #pragma unroll
    for (int m=0;m<4;++m) { a0[m][0]=aLoad(1,m,0); a0[m][1]=aLoad(1,m,1); }
    #pragma unroll
    for (int n=0;n<2;++n) { b0[n][0]=bLoad(1,n,0); b0[n][1]=bLoad(1,n,1); }
    stage(0, tn0, 1, 0);
    bar();
    __builtin_amdgcn_s_setprio(1);
    #pragma unroll
    for (int m=0;m<4;++m)
      #pragma unroll
      for (int n=0;n<2;++n) {
        acc[m][n] = __builtin_amdgcn_mfma_f32_16x16x32_bf16(a0[m][0], b0[n][0], acc[m][n],0,0,0);
        acc[m][n] = __builtin_amdgcn_mfma_f32_16x16x32_bf16(a0[m][1], b0[n][1], acc[m][n],0,0,0);
      }
    __builtin_amdgcn_s_setprio(0);
    bar();

    // -- P6: read B[2..3] slot1; stage tn0 B.h0; mfma q'(0,1)
    #pragma unroll
    for (int n=0;n<2;++n) { b1[n][0]=bLoad(1,n+2,0); b1[n][1]=bLoad(1,n+2,1); }
    stage(1, tn0, 0, 0);
    bar();
    __builtin_amdgcn_s_setprio(1);
    #pragma unroll
    for (int m=0;m<4;++m)
      #pragma unroll
      for (int n=0;n<2;++n) {
        acc[m][n+2] = __builtin_amdgcn_mfma_f32_16x16x32_bf16(a0[m][0], b1[n][0], acc[m][n+2],0,0,0);
        acc[m][n+2] = __builtin_amdgcn_mfma_f32_16x16x32_bf16(a0[m][1], b1[n][1], acc[m][n+2],0,0,0);
      }
    __builtin_amdgcn_s_setprio(0);
    bar();

    // -- P7: read A[4..7] slot1; stage tn0 B.h1; mfma q'(1,1)
    #pragma unroll
    for (int m=0;m<4;++m) { a1[m][0]=aLoad(1,m+4,0); a1[m][1]=aLoad(1,m+4,1); }
    stage(1, tn0, 1, 0);
    bar();
    __builtin_amdgcn_s_setprio(1);
    #pragma unroll
    for (int m=0;m<4;++m)
      #pragma unroll
      for (int n=0;n<2;++n) {
        acc[m+4][n+2] = __builtin_amdgcn_mfma_f32_16x16x32_bf16(a1[m][0], b1[n][0], acc[m+4][n+2],0,0,0);
        acc[m+4][n+2] = __builtin_amdgcn_mfma_f32_16x16x32_bf16(a1[m][1], b1[n][1], acc[m+4][n+2],0,0,0);
      }
    __builtin_amdgcn_s_setprio(0);
    bar();

    // -- P8: stage tn1 A.h0 -> slot1; vmcnt(2) => tn0 (next slot0) resident; mfma q'(1,0)
    stage(0, tn1, 0, 1);
    asm volatile("s_waitcnt vmcnt(2)" ::: "memory");
    bar();
    __builtin_amdgcn_s_setprio(1);
    #pragma unroll
    for (int m=0;m<4;++m)
      #pragma unroll
      for (int n=0;n<2;++n) {
        acc[m+4][n] = __builtin_amdgcn_mfma_f32_16x16x32_bf16(a1[m][0], b0[n][0], acc[m+4][n],0,0,0);
        acc[m+4][n] = __builtin_amdgcn_mfma_f32_16x16x32_bf16(a1[m][1], b0[n][1], acc[m+4][n],0,0,0);
      }
    __builtin_amdgcn_s_setprio(0);
    bar();
  }

  const long rowbase = (long)bm*256 + wr*128;
  const long colbase = (long)bn*256 + wc*64;

  if constexpr (EPI == EPI_LMHEAD) {
    #pragma unroll
    for (int m=0;m<8;++m)
      #pragma unroll
      for (int n=0;n<4;++n) {
        long c = colbase + n*16 + l15;
        float bv = bias[c];
        #pragma unroll
        for (int q_=0;q_<4;++q_) {
          acc[m][n][q_] += bv;
          long rr = rowbase + m*16 + g*4 + q_;
          __builtin_nontemporal_store(acc[m][n][q_], &outf[rr*ldo + c]);
        }
      }
    __syncthreads();   // drains vmcnt too -> safe smem reuse
    float* redm = (float*)smem;       // [4][256]
    float* reds = redm + 1024;
    #pragma unroll
    for (int m=0;m<8;++m)
      #pragma unroll
      for (int q_=0;q_<4;++q_) {
        float mx = fmaxf(fmaxf(acc[m][0][q_], acc[m][1][q_]),
                         fmaxf(acc[m][2][q_], acc[m][3][q_]));
        #pragma unroll
        for (int msk=8;msk>=1;msk>>=1) mx = fmaxf(mx, __shfl_xor(mx, msk));
        float se = 0.f;
        #pragma unroll
        for (int n=0;n<4;++n) se += __expf(acc[m][n][q_] - mx);
        #pragma unroll
        for (int msk=8;msk>=1;msk>>=1) se += __shfl_xor(se, msk);
        if (l15 == 0) {
          int rloc = wr*128 + m*16 + g*4 + q_;
          redm[wc*256 + rloc] = mx;
          reds[wc*256 + rloc] = se;
        }
      }
    __syncthreads();
    if (tid < 256) {
      float m0=redm[tid], m1=redm[256+tid], m2=redm[512+tid], m3=redm[768+tid];
      float M = fmaxf(fmaxf(m0,m1), fmaxf(m2,m3));
      float Sv = reds[tid]*__expf(m0-M) + reds[256+tid]*__expf(m1-M)
               + reds[512+tid]*__expf(m2-M) + reds[768+tid]*__expf(m3-M);
      long row = (long)bm*256 + tid;
      pmax[row*NCHUNK + bn] = M;
      psum[row*NCHUNK + bn] = Sv;
    }
  } else {
    #pragma unroll
    for (int m=0;m<8;++m)
      #pragma unroll
      for (int n=0;n<4;++n) {
        long c = colbase + n*16 + l15;
        #pragma unroll
        for (int q_=0;q_<4;++q_) {
          long rr = rowbase + m*16 + g*4 + q_;
          float v = acc[m][n][q_];
          if constexpr (EPI == EPI_F32) {
            outf[(long)bz*sOb + rr*ldo + c] = v;
          } else if constexpr (EPI == EPI_BF16) {
            outb[(long)bz*sOb + rr*ldo + c] = (bf16)v;
          } else if constexpr (EPI == EPI_BIAS_RELU_BF16) {
            outb[rr*ldo + c] = (bf16)fmaxf(v + bias[c], 0.f);
          } else if constexpr (EPI == EPI_BIAS_RES_BF16) {
            outb[rr*ldo + c] = (bf16)(v + bias[c] + res[rr*ldr + c]);
          } else if constexpr (EPI == EPI_RES_F32) {
            outf[(long)bz*sOb + rr*ldo + c] = v + res[(long)bz*sRb + rr*ldr + c];
          }
        }
      }
  }
}

// ---------------- loss pass 1 ----------------
__global__ __launch_bounds__(256)
void loss1_kernel(const float* __restrict__ pmax, const float* __restrict__ psum,
                  const float* __restrict__ logits, const int* __restrict__ targets,
                  float* __restrict__ rowloss) {
  int row = blockIdx.x;
  int tid = threadIdx.x;
  int lane = tid & 63, wv = tid >> 6;
  float cm = (tid < NCHUNK) ? pmax[(long)row*NCHUNK + tid] : -1e30f;
  float cs = (tid < NCHUNK) ? psum[(long)row*NCHUNK + tid] : 0.f;
  float mx = cm;
  #pragma unroll
  for (int m=32;m>=1;m>>=1) mx = fmaxf(mx, __shfl_xor(mx, m));
  __shared__ float rm[4];
  if (lane == 0) rm[wv] = mx;
  __syncthreads();
  float M = fmaxf(fmaxf(rm[0],rm[1]), fmaxf(rm[2],rm[3]));
  float sc = cs * __expf(cm - M);
  #pragma unroll
  for (int m=32;m>=1;m>>=1) sc += __shfl_xor(sc, m);
  __shared__ float rs_[4];
  if (lane == 0) rs_[wv] = sc;
  __syncthreads();
  if (tid == 0) {
    float Sv = rs_[0]+rs_[1]+rs_[2]+rs_[3];
    float lse = M + logf(Sv);
    int tgt = targets[row];
    float lg = logits[(long)row*NV + tgt];
    rowloss[row] = lse - lg;
  }
}

// ---------------- loss pass 2 ----------------
__global__ __launch_bounds__(256)
void loss2_kernel(const float* __restrict__ rowloss, float* __restrict__ out) {
  int tid = threadIdx.x;
  float s = 0.f;
  for (int i = tid; i < NROWS; i += 256) s += rowloss[i];
  #pragma unroll
  for (int m=32;m>=1;m>>=1) s += __shfl_xor(s, m);
  __shared__ float rs_[4];
  if ((tid & 63) == 0) rs_[tid>>6] = s;
  __syncthreads();
  if (tid == 0) out[0] = (rs_[0]+rs_[1]+rs_[2]+rs_[3]) * (1.f/NROWS);
}

// ---------------- launcher ----------------
extern "C" void kernel_launch(void* const* d_in, const int* in_sizes, int n_in,
                              void* d_out, int out_size, void* d_ws, size_t ws_size,
                              hipStream_t stream) {
  const int*   idx  = (const int*)d_in[0];
  const int*   tgt  = (const int*)d_in[1];
  const float* tok  = (const float*)d_in[2];
  const float* pos  = (const float*)d_in[3];
  const float* Wk   = (const float*)d_in[4];
  const float* Wq   = (const float*)d_in[5];
  const float* Wv   = (const float*)d_in[6];
  const float* W1   = (const float*)d_in[7];
  const float* b1   = (const float*)d_in[8];
  const float* W2   = (const float*)d_in[9];
  const float* b2   = (const float*)d_in[10];
  const float* g1   = (const float*)d_in[11];
  const float* be1  = (const float*)d_in[12];
  const float* g2   = (const float*)d_in[13];
  const float* be2  = (const float*)d_in[14];
  const float* Wlm  = (const float*)d_in[15];
  const float* blm  = (const float*)d_in[16];

  float* logits = (float*)d_out;
  float* loss   = logits + (long)NROWS*NV;

  char* w = (char*)d_ws;
  auto alloc = [&](size_t bytes) -> char* {
    char* p = w; w += (bytes + 255) & ~(size_t)255; return p;
  };
  bf16* wqkvb = (bf16*)alloc((size_t)3*NC*NC*2);   // [1536][512]: Wq,Wk,Wv stacked
  bf16* w1b   = (bf16*)alloc((size_t)4*NC*NC*2);
  bf16* w2b   = (bf16*)alloc((size_t)4*NC*NC*2);
  bf16* wlmb  = (bf16*)alloc((size_t)NV*NC*2);
  float* x0   = (float*)alloc((size_t)NROWS*NC*4);
  bf16* h1b   = (bf16*)alloc((size_t)NROWS*NC*2);
  bf16* qkvb  = (bf16*)alloc((size_t)NROWS*3*NC*2); // [8192][1536]
  bf16* vtb   = (bf16*)alloc((size_t)NROWS*NC*2);
  float* Sb   = (float*)alloc((size_t)NB*NT*NT*4);  // P (bf16) aliased inside
  float* x1   = (float*)alloc((size_t)NROWS*NC*4);
  bf16* h2b   = (bf16*)alloc((size_t)NROWS*NC*2);
  bf16* ffb   = (bf16*)alloc((size_t)NROWS*4*NC*2);
  bf16* x2b   = (bf16*)alloc((size_t)NROWS*NC*2);
  float* pmax = (float*)alloc((size_t)NROWS*NCHUNK*4);
  float* psum = (float*)alloc((size_t)NROWS*NCHUNK*4);
  float* rowloss = (float*)alloc((size_t)NROWS*4);

  hipFuncSetAttribute((const void*)gemm256<EPI_BF16,false,false,false>,
                      hipFuncAttributeMaxDynamicSharedMemorySize, SMEM_B);
  hipFuncSetAttribute((const void*)gemm256<EPI_F32,true,false,false>,
                      hipFuncAttributeMaxDynamicSharedMemorySize, SMEM_B);
  hipFuncSetAttribute((const void*)gemm256<EPI_RES_F32,false,true,false>,
                      hipFuncAttributeMaxDynamicSharedMemorySize, SMEM_B);
  hipFuncSetAttribute((const void*)gemm256<EPI_BIAS_RELU_BF16,false,false,false>,
                      hipFuncAttributeMaxDynamicSharedMemorySize, SMEM_B);
  hipFuncSetAttribute((const void*)gemm256<EPI_BIAS_RES_BF16,false,false,false>,
                      hipFuncAttributeMaxDynamicSharedMemorySize, SMEM_B);
  hipFuncSetAttribute((const void*)gemm256<EPI_LMHEAD,false,false,true>,
                      hipFuncAttributeMaxDynamicSharedMemorySize, SMEM_B);

  auto cvt = [&](const float* in, bf16* out, long n) {
    int n8 = (int)(n/8);
    int blocks = (n8 + 255)/256; if (blocks > 2048) blocks = 2048;
    cvt_kernel<<<blocks, 256, 0, stream>>>(in, out, n8);
  };
  cvt(Wq, wqkvb, (long)NC*NC);
  cvt(Wk, wqkvb + (long)NC*NC, (long)NC*NC);
  cvt(Wv, wqkvb + (long)2*NC*NC, (long)NC*NC);
  cvt(W1, w1b, (long)4*NC*NC);
  cvt(W2, w2b, (long)4*NC*NC);
  cvt(Wlm, wlmb, (long)NV*NC);

  embed_kernel<<<NROWS, 64, 0, stream>>>(idx, tok, pos, x0);
  ln_kernel<<<NROWS, 64, 0, stream>>>(x0, g1, be1, h1b);

  // fused QKV: qkv[8192][1536] = h1 * Wqkv^T
  gemm256<EPI_BF16><<<dim3(6,32,1), 512, SMEM_B, stream>>>(
      h1b, wqkvb, 8, NC, NC, 0, 0, nullptr, qkvb, 3*NC, 0,
      nullptr, nullptr, 0, 0, nullptr, nullptr);

  transpose_kernel<<<dim3(NT/64, NC/64, NB), 256, 0, stream>>>(qkvb + 2*NC, 3*NC, vtb);

  // S = q k^T (per batch), causal block skip
  gemm256<EPI_F32,true><<<dim3(8,8,NB), 512, SMEM_B, stream>>>(
      qkvb, qkvb + NC, 8, 3*NC, 3*NC, (long)NT*3*NC, (long)NT*3*NC,
      Sb, nullptr, NT, (long)NT*NT,
      nullptr, nullptr, 0, 0, nullptr, nullptr);

  softmax_kernel<<<NROWS, 256, 0, stream>>>(Sb);

  // x1 = x0 + P vT^T (per batch), causal K-limit
  gemm256<EPI_RES_F32,false,true><<<dim3(2,8,NB), 512, SMEM_B, stream>>>(
      (const bf16*)Sb, vtb, 32, 2*NT, NT, (long)NT*2*NT, (long)NC*NT,
      x1, nullptr, NC, (long)NT*NC,
      nullptr, x0, NC, (long)NT*NC, nullptr, nullptr);

  ln_kernel<<<NROWS, 64, 0, stream>>>(x1, g2, be2, h2b);

  // ff = relu(h2 W1^T + b1)
  gemm256<EPI_BIAS_RELU_BF16><<<dim3(8,32,1), 512, SMEM_B, stream>>>(
      h2b, w1b, 8, NC, NC, 0, 0, nullptr, ffb, 4*NC, 0,
      b1, nullptr, 0, 0, nullptr, nullptr);

  // x2 = x1 + ff W2^T + b2
  gemm256<EPI_BIAS_RES_BF16><<<dim3(2,32,1), 512, SMEM_B, stream>>>(
      ffb, w2b, 32, 4*NC, 4*NC, 0, 0, nullptr, x2b, NC, 0,
      b2, x1, NC, 0, nullptr, nullptr);

  // logits + per-256-col-chunk (max,sumexp) partials
  gemm256<EPI_LMHEAD,false,false,true><<<dim3(NCHUNK,32,1), 512, SMEM_B, stream>>>(
      x2b, wlmb, 8, NC, NC, 0, 0, logits, nullptr, NV, 0,
      blm, nullptr, 0, 0, pmax, psum);

  loss1_kernel<<<NROWS, 256, 0, stream>>>(pmax, psum, logits, tgt, rowloss);
  loss2_kernel<<<1, 256, 0, stream>>>(rowloss, loss);
}

// Round 4
// 774.136 us; speedup vs baseline: 1.1599x; 1.0167x over previous
//
#include <hip/hip_runtime.h>

typedef __bf16 bf16;
typedef __bf16 bf16x8 __attribute__((ext_vector_type(8)));
typedef float  f32x4  __attribute__((ext_vector_type(4)));

#define NB 4
#define NT 2048
#define NC 512
#define NV 32000
#define NROWS (NB*NT)          // 8192
#define NCHUNK (NV/256)        // 125
#define LNEPS 1e-5f
#define SMEM_B 131072

static __device__ __forceinline__ void load_lds16(const bf16* g, char* l) {
  __builtin_amdgcn_global_load_lds(
      (const __attribute__((address_space(1))) void*)g,
      (__attribute__((address_space(3))) void*)l, 16, 0, 0);
}

static __device__ __forceinline__ void bar() {
  asm volatile("" ::: "memory");
  __builtin_amdgcn_s_barrier();
  asm volatile("" ::: "memory");
}

// ---------------- f32 -> bf16 convert (vectorized x8) ----------------
__global__ __launch_bounds__(256)
void cvt_kernel(const float* __restrict__ in, bf16* __restrict__ out, int n8) {
  long i = (long)blockIdx.x * 256 + threadIdx.x;
  long stride = (long)gridDim.x * 256;
  for (; i < n8; i += stride) {
    const float* p = in + i * 8;
    f32x4 a = *(const f32x4*)p;
    f32x4 b = *(const f32x4*)(p + 4);
    bf16x8 o;
    o[0]=(bf16)a.x; o[1]=(bf16)a.y; o[2]=(bf16)a.z; o[3]=(bf16)a.w;
    o[4]=(bf16)b.x; o[5]=(bf16)b.y; o[6]=(bf16)b.z; o[7]=(bf16)b.w;
    *(bf16x8*)(out + i*8) = o;
  }
}

// ---------------- fused embedding + layernorm1 ----------------
__global__ __launch_bounds__(64)
void embed_ln_kernel(const int* __restrict__ idx, const float* __restrict__ tok,
                     const float* __restrict__ pos, const float* __restrict__ gw,
                     const float* __restrict__ bw,
                     float* __restrict__ x0, bf16* __restrict__ h1) {
  int row = blockIdx.x;
  int t = row & (NT-1);
  int id = idx[row];
  int lane = threadIdx.x;
  const float* tr = tok + (long)id*NC + lane*8;
  const float* pr = pos + (long)t*NC + lane*8;
  f32x4 a0 = *(const f32x4*)tr, a1 = *(const f32x4*)(tr+4);
  f32x4 p0 = *(const f32x4*)pr, p1 = *(const f32x4*)(pr+4);
  f32x4 r0 = a0 + p0, r1 = a1 + p1;
  float* o = x0 + (long)row*NC + lane*8;
  *(f32x4*)o = r0; *(f32x4*)(o+4) = r1;
  float v[8] = {r0.x,r0.y,r0.z,r0.w,r1.x,r1.y,r1.z,r1.w};
  float s = 0.f;
  #pragma unroll
  for (int j=0;j<8;++j) s += v[j];
  #pragma unroll
  for (int m=32;m>=1;m>>=1) s += __shfl_xor(s, m);
  float mu = s * (1.f/NC);
  float sq = 0.f;
  #pragma unroll
  for (int j=0;j<8;++j) { v[j] -= mu; sq += v[j]*v[j]; }
  #pragma unroll
  for (int m=32;m>=1;m>>=1) sq += __shfl_xor(sq, m);
  float rs = rsqrtf(sq * (1.f/NC) + LNEPS);
  const float* gp = gw + lane*8;
  const float* bp = bw + lane*8;
  f32x4 g0 = *(const f32x4*)gp, g1 = *(const f32x4*)(gp+4);
  f32x4 b0 = *(const f32x4*)bp, b1 = *(const f32x4*)(bp+4);
  float gg[8] = {g0.x,g0.y,g0.z,g0.w,g1.x,g1.y,g1.z,g1.w};
  float bb[8] = {b0.x,b0.y,b0.z,b0.w,b1.x,b1.y,b1.z,b1.w};
  bf16x8 oo;
  #pragma unroll
  for (int j=0;j<8;++j) oo[j] = (bf16)(v[j]*rs*gg[j] + bb[j]);
  *(bf16x8*)(h1 + (long)row*NC + lane*8) = oo;
}

// ---------------- layernorm: one wave per row of 512 ----------------
__global__ __launch_bounds__(64)
void ln_kernel(const float* __restrict__ x, const float* __restrict__ gw,
               const float* __restrict__ bw, bf16* __restrict__ out) {
  int row = blockIdx.x;
  int lane = threadIdx.x;
  const float* xr = x + (long)row*NC + lane*8;
  f32x4 a = *(const f32x4*)xr;
  f32x4 b = *(const f32x4*)(xr+4);
  float v[8] = {a.x,a.y,a.z,a.w,b.x,b.y,b.z,b.w};
  float s = 0.f;
  #pragma unroll
  for (int j=0;j<8;++j) s += v[j];
  #pragma unroll
  for (int m=32;m>=1;m>>=1) s += __shfl_xor(s, m);
  float mu = s * (1.f/NC);
  float sq = 0.f;
  #pragma unroll
  for (int j=0;j<8;++j) { v[j] -= mu; sq += v[j]*v[j]; }
  #pragma unroll
  for (int m=32;m>=1;m>>=1) sq += __shfl_xor(sq, m);
  float rs = rsqrtf(sq * (1.f/NC) + LNEPS);
  const float* gp = gw + lane*8;
  const float* bp = bw + lane*8;
  f32x4 g0 = *(const f32x4*)gp, g1 = *(const f32x4*)(gp+4);
  f32x4 b0 = *(const f32x4*)bp, b1 = *(const f32x4*)(bp+4);
  float gg[8] = {g0.x,g0.y,g0.z,g0.w,g1.x,g1.y,g1.z,g1.w};
  float bb[8] = {b0.x,b0.y,b0.z,b0.w,b1.x,b1.y,b1.z,b1.w};
  bf16x8 o;
  #pragma unroll
  for (int j=0;j<8;++j) o[j] = (bf16)(v[j]*rs*gg[j] + bb[j]);
  *(bf16x8*)(out + (long)row*NC + lane*8) = o;
}

// ---------------- transpose v[b][t][c] (stride ldv) -> vt[b][c][t] ----------------
__global__ __launch_bounds__(256)
void transpose_kernel(const bf16* __restrict__ v, long ldv, bf16* __restrict__ vt) {
  __shared__ bf16 tile[64][66];
  int b = blockIdx.z;
  int t0 = blockIdx.x*64, c0 = blockIdx.y*64;
  int tid = threadIdx.x;
  int r = tid >> 2, ch = (tid & 3) * 16;
  const bf16* src = v + ((long)b*NT + t0 + r)*ldv + c0 + ch;
  #pragma unroll
  for (int i=0;i<16;++i) tile[r][ch+i] = src[i];
  __syncthreads();
  bf16x8 o0, o1;
  #pragma unroll
  for (int i=0;i<8;++i) o0[i] = tile[ch+i][r];
  #pragma unroll
  for (int i=0;i<8;++i) o1[i] = tile[ch+8+i][r];
  bf16* dst = vt + ((long)b*NC + c0 + r)*NT + t0 + ch;
  *(bf16x8*)dst = o0;
  *(bf16x8*)(dst+8) = o1;
}

// ---------------- causal softmax row: S f32 -> P bf16 (aliased into S) ----------------
__global__ __launch_bounds__(256)
void softmax_kernel(float* __restrict__ S) {
  const int row = blockIdx.x;
  const int t = row & (NT-1);
  const int tid = threadIdx.x;
  float* sr = S + (long)row*NT;
  bf16* pr = (bf16*)S + (long)row*(2*NT);
  const float scale = 0.044194173824159216f;
  f32x4 v0 = *(const f32x4*)(sr + tid*8);
  f32x4 v1 = *(const f32x4*)(sr + tid*8 + 4);
  float v[8] = {v0.x,v0.y,v0.z,v0.w,v1.x,v1.y,v1.z,v1.w};
  int cb = tid*8;
  float mx = -1e30f;
  #pragma unroll
  for (int j=0;j<8;++j) {
    v[j] = (cb + j <= t) ? v[j]*scale : -1e30f;
    mx = fmaxf(mx, v[j]);
  }
  __shared__ float redm[4];
  #pragma unroll
  for (int m=32;m>=1;m>>=1) mx = fmaxf(mx, __shfl_xor(mx, m));
  if ((tid & 63) == 0) redm[tid>>6] = mx;
  __syncthreads();
  mx = fmaxf(fmaxf(redm[0],redm[1]), fmaxf(redm[2],redm[3]));
  float e[8]; float s = 0.f;
  #pragma unroll
  for (int j=0;j<8;++j) { e[j] = (cb + j <= t) ? __expf(v[j]-mx) : 0.f; s += e[j]; }
  __shared__ float reds[4];
  #pragma unroll
  for (int m=32;m>=1;m>>=1) s += __shfl_xor(s, m);
  if ((tid & 63) == 0) reds[tid>>6] = s;
  __syncthreads();
  s = reds[0]+reds[1]+reds[2]+reds[3];
  float inv = 1.f/s;
  bf16x8 o;
  #pragma unroll
  for (int j=0;j<8;++j) o[j] = (bf16)(e[j]*inv);
  *(bf16x8*)(pr + cb) = o;
}

// ======== 256x256-tile 8-phase GEMM: out[M,N] = A[M,K] * B[N,K]^T ========
// 512 threads = 8 waves (2 wr x 4 wc); per-wave 128x64 out; BK=64; LDS 128KB.
// SWAP=true: bm = blockIdx.x (fast), bn = blockIdx.y (slow) -> all XCDs share
// one B-panel at a time (B-panel L2-resident, fetched once from HBM).
enum { EPI_F32=0, EPI_BF16=1, EPI_BIAS_RELU_BF16=2, EPI_BIAS_RES_BF16=3, EPI_RES_F32=4, EPI_LMHEAD=5 };

template<int EPI, bool CAUSAL=false, bool KLIMIT=false, bool SWAP=false>
__global__ __launch_bounds__(512,2)
void gemm256(const bf16* __restrict__ A, const bf16* __restrict__ B, int nkt,
             long lda, long ldb, long sAb, long sBb,
             float* __restrict__ outf, bf16* __restrict__ outb, long ldo, long sOb,
             const float* __restrict__ bias,
             const float* __restrict__ res, long ldr, long sRb,
             float* __restrict__ pmax, float* __restrict__ psum) {
  extern __shared__ char smem[];
  int bn, bm;
  if constexpr (SWAP) { bm = blockIdx.x; bn = blockIdx.y; }
  else               { bn = blockIdx.x; bm = blockIdx.y; }
  const int bz = blockIdx.z;
  if constexpr (CAUSAL) { if (bn > bm) return; }
  int nkt_eff = nkt;
  if constexpr (KLIMIT) { int c = (bm+1)*4; if (c < nkt_eff) nkt_eff = c; }

  const int tid = threadIdx.x;
  const int wid = tid >> 6, lane = tid & 63;
  const int wr = wid >> 2, wc = wid & 3;
  const int l15 = lane & 15, g = lane >> 4;

  const bf16* Ab = A + (long)bz*sAb + (long)bm*256*lda;
  const bf16* Bb = B + (long)bz*sBb + (long)bn*256*ldb;

  // source pre-swizzle: thread covers lds row (tid>>3), byte col (tid&7)*16;
  // must fetch global byte col ((tid&7)*16) ^ (((tid>>3)&7)<<4)
  const int colsw = 8 * ((tid & 7) ^ ((tid >> 3) & 7));
  const bf16* A0 = Ab + (long)(tid >> 3)*lda + colsw;
  const bf16* B0 = Bb + (long)(tid >> 3)*ldb + colsw;

  // stage half-tile: ab=0 A, ab=1 B; h=0/1; slot=0/1; tile t
  auto stage = [&](int ab, int t, int h, int slot) {
    char* dst = smem + slot*65536 + ab*32768 + h*16384 + wid*1024;
    const bf16* s0 = (ab ? B0 : A0) + (long)(h*128)*(ab ? ldb : lda) + (long)t*64;
    load_lds16(s0, dst);
    load_lds16(s0 + 64*(ab ? ldb : lda), dst + 8192);
  };

  const char* sm = smem;
  auto aLoad = [&](int slot, int m, int kk) -> bf16x8 {
    int row = m*16 + l15;
    int b = row*128 + ((kk*64 + g*16) ^ ((row & 7) << 4));
    return *(const bf16x8*)(sm + slot*65536 + wr*16384 + b);
  };
  auto bLoad = [&](int slot, int n, int kk) -> bf16x8 {
    int row = (wc & 1)*64 + n*16 + l15;
    int b = row*128 + ((kk*64 + g*16) ^ ((row & 7) << 4));
    return *(const bf16x8*)(sm + slot*65536 + 32768 + (wc >> 1)*16384 + b);
  };

  f32x4 acc[8][4] = {};

  // prologue: tile0 fully into slot0, tile1 half A.h0 into slot1
  stage(0, 0, 0, 0);
  stage(0, 0, 1, 0);
  stage(1, 0, 0, 0);
  stage(1, 0, 1, 0);
  stage(0, 1, 0, 1);
  asm volatile("s_waitcnt vmcnt(2)" ::: "memory");
  bar();

  const int niter = nkt_eff >> 1;
  for (int it = 0; it < niter; ++it) {
    const int t0 = 2*it, t1 = 2*it + 1;
    const int tn0 = (t0+2 < nkt_eff) ? t0+2 : nkt_eff-1;
    const int tn1 = (t1+2 < nkt_eff) ? t1+2 : nkt_eff-1;
    bf16x8 a0[4][2], a1[4][2], b0[2][2], b1[2][2];

    // -- P1: read A[0..3],B[0..1] slot0; stage t1 A.h1; mfma q(0,0)
    #pragma unroll
    for (int m=0;m<4;++m) { a0[m][0]=aLoad(0,m,0); a0[m][1]=aLoad(0,m,1); }
    #pragma unroll
    for (int n=0;n<2;++n) { b0[n][0]=bLoad(0,n,0); b0[n][1]=bLoad(0,n,1); }
    stage(0, t1, 1, 1);
    bar();
    __builtin_amdgcn_s_setprio(1);
    #pragma unroll
    for (int m=0;m<4;++m)
      #pragma unroll
      for (int n=0;n<2;++n) {
        acc[m][n] = __builtin_amdgcn_mfma_f32_16x16x32_bf16(a0[m][0], b0[n][0], acc[m][n],0,0,0);
        acc[m][n] = __builtin_amdgcn_mfma_f32_16x16x32_bf16(a0[m][1], b0[n][1], acc[m][n],0,0,0);
      }
    __builtin_amdgcn_s_setprio(0);
    bar();

    // -- P2: read B[2..3] slot0; stage t1 B.h0; mfma q(0,1)
    #pragma unroll
    for (int n=0;n<2;++n) { b1[n][0]=bLoad(0,n+2,0); b1[n][1]=bLoad(0,n+2,1); }
    stage(1, t1, 0, 1);
    bar();
    __builtin_amdgcn_s_setprio(1);
    #pragma unroll
    for (int m=0;m<4;++m)
      #pragma unroll
      for (int n=0;n<2;++n) {
        acc[m][n+2] = __builtin_amdgcn_mfma_f32_16x16x32_bf16(a0[m][0], b1[n][0], acc[m][n+2],0,0,0);
        acc[m][n+2] = __builtin_amdgcn_mfma_f32_16x16x32_bf16(a0[m][1], b1[n][1], acc[m][n+2],0,0,0);
      }
    __builtin_amdgcn_s_setprio(0);
    bar();

    // -- P3: read A[4..7] slot0; stage t1 B.h1; mfma q(1,1)
    #pragma unroll
    for (int m=0;m<4;++m) { a1[m][0]=aLoad(0,m+4,0); a1[m][1]=aLoad(0,m+4,1); }
    stage(1, t1, 1, 1);
    bar();
    __builtin_amdgcn_s_setprio(1);
    #pragma unroll
    for (int m=0;m<4;++m)
      #pragma unroll
      for (int n=0;n<2;++n) {
        acc[m+4][n+2] = __builtin_amdgcn_mfma_f32_16x16x32_bf16(a1[m][0], b1[n][0], acc[m+4][n+2],0,0,0);
        acc[m+4][n+2] = __builtin_amdgcn_mfma_f32_16x16x32_bf16(a1[m][1], b1[n][1], acc[m+4][n+2],0,0,0);
      }
    __builtin_amdgcn_s_setprio(0);
    bar();

    // -- P4: stage tn0 A.h0 -> slot0; vmcnt(2) => t1 fully resident; mfma q(1,0)
    stage(0, tn0, 0, 0);
    asm volatile("s_waitcnt vmcnt(2)" ::: "memory");
    bar();
    __builtin_amdgcn_s_setprio(1);
    #pragma unroll
    for (int m=0;m<4;++m)
      #pragma unroll
      for (int n=0;n<2;++n) {
        acc[m+4][n] = __builtin_amdgcn_mfma_f32_16x16x32_bf16(a1[m][0], b0[n][0], acc[m+4][n],0,0,0);
        acc[m+4][n] = __builtin_amdgcn_mfma_f32_16x16x32_bf16(a1[m][1], b0[n][1], acc[m+4][n],0,0,0);
      }
    __builtin_amdgcn_s_setprio(0);
    bar();

    // -- P5: read A[0..3],B[0..1] slot1; stage tn0 A.h1; mfma q'(0,0)
    #pragma unroll
    for (int m=0;m<4;++m) { a0[m][0]=aLoad(1,m,0); a0[m][1]=aLoad(1,m,1); }
    #pragma unroll
    for (int n=0;n<2;++n) { b0[n][0]=bLoad(1,n,0); b0[n][1]=bLoad(1,n,1); }
    stage(0, tn0, 1, 0);
    bar();
    __builtin_amdgcn_s_setprio(1);
    #pragma unroll
    for (int m=0;m<4;++m)
      #pragma unroll
      for (int n=0;n<2;++n) {
        acc[m][n] = __builtin_amdgcn_mfma_f32_16x16x32_bf16(a0[m][0], b0[n][0], acc[m][n],0,0,0);
        acc[m][n] = __builtin_amdgcn_mfma_f32_16x16x32_bf16(a0[m][1], b0[n][1], acc[m][n],0,0,0);
      }
    __builtin_amdgcn_s_setprio(0);
    bar();

    // -- P6: read B[2..3] slot1; stage tn0 B.h0; mfma q'(0,1)
    #pragma unroll
    for (int n=0;n<2;++n) { b1[n][0]=bLoad(1,n+2,0); b1[n][1]=bLoad(1,n+2,1); }
    stage(1, tn0, 0, 0);
    bar();
    __builtin_amdgcn_s_setprio(1);
    #pragma unroll
    for (int m=0;m<4;++m)
      #pragma unroll
      for (int n=0;n<2;++n) {
        acc[m][n+2] = __builtin_amdgcn_mfma_f32_16x16x32_bf16(a0[m][0], b1[n][0], acc[m][n+2],0,0,0);
        acc[m][n+2] = __builtin_amdgcn_mfma_f32_16x16x32_bf16(a0[m][1], b1[n][1], acc[m][n+2],0,0,0);
      }
    __builtin_amdgcn_s_setprio(0);
    bar();

    // -- P7: read A[4..7] slot1; stage tn0 B.h1; mfma q'(1,1)
    #pragma unroll
    for (int m=0;m<4;++m) { a1[m][0]=aLoad(1,m+4,0); a1[m][1]=aLoad(1,m+4,1); }
    stage(1, tn0, 1, 0);
    bar();
    __builtin_amdgcn_s_setprio(1);
    #pragma unroll
    for (int m=0;m<4;++m)
      #pragma unroll
      for (int n=0;n<2;++n) {
        acc[m+4][n+2] = __builtin_amdgcn_mfma_f32_16x16x32_bf16(a1[m][0], b1[n][0], acc[m+4][n+2],0,0,0);
        acc[m+4][n+2] = __builtin_amdgcn_mfma_f32_16x16x32_bf16(a1[m][1], b1[n][1], acc[m+4][n+2],0,0,0);
      }
    __builtin_amdgcn_s_setprio(0);
    bar();

    // -- P8: stage tn1 A.h0 -> slot1; vmcnt(2) => tn0 (next slot0) resident; mfma q'(1,0)
    stage(0, tn1, 0, 1);
    asm volatile("s_waitcnt vmcnt(2)" ::: "memory");
    bar();
    __builtin_amdgcn_s_setprio(1);
    #pragma unroll
    for (int m=0;m<4;++m)
      #pragma unroll
      for (int n=0;n<2;++n) {
        acc[m+4][n] = __builtin_amdgcn_mfma_f32_16x16x32_bf16(a1[m][0], b0[n][0], acc[m+4][n],0,0,0);
        acc[m+4][n] = __builtin_amdgcn_mfma_f32_16x16x32_bf16(a1[m][1], b0[n][1], acc[m+4][n],0,0,0);
      }
    __builtin_amdgcn_s_setprio(0);
    bar();
  }

  const long rowbase = (long)bm*256 + wr*128;
  const long colbase = (long)bn*256 + wc*64;

  if constexpr (EPI == EPI_LMHEAD) {
    #pragma unroll
    for (int m=0;m<8;++m)
      #pragma unroll
      for (int n=0;n<4;++n) {
        long c = colbase + n*16 + l15;
        float bv = bias[c];
        #pragma unroll
        for (int q_=0;q_<4;++q_) {
          acc[m][n][q_] += bv;
          long rr = rowbase + m*16 + g*4 + q_;
          __builtin_nontemporal_store(acc[m][n][q_], &outf[rr*ldo + c]);
        }
      }
    __syncthreads();   // drains vmcnt too -> safe smem reuse
    float* redm = (float*)smem;       // [4][256]
    float* reds = redm + 1024;
    #pragma unroll
    for (int m=0;m<8;++m)
      #pragma unroll
      for (int q_=0;q_<4;++q_) {
        float mx = fmaxf(fmaxf(acc[m][0][q_], acc[m][1][q_]),
                         fmaxf(acc[m][2][q_], acc[m][3][q_]));
        #pragma unroll
        for (int msk=8;msk>=1;msk>>=1) mx = fmaxf(mx, __shfl_xor(mx, msk));
        float se = 0.f;
        #pragma unroll
        for (int n=0;n<4;++n) se += __expf(acc[m][n][q_] - mx);
        #pragma unroll
        for (int msk=8;msk>=1;msk>>=1) se += __shfl_xor(se, msk);
        if (l15 == 0) {
          int rloc = wr*128 + m*16 + g*4 + q_;
          redm[wc*256 + rloc] = mx;
          reds[wc*256 + rloc] = se;
        }
      }
    __syncthreads();
    if (tid < 256) {
      float m0=redm[tid], m1=redm[256+tid], m2=redm[512+tid], m3=redm[768+tid];
      float M = fmaxf(fmaxf(m0,m1), fmaxf(m2,m3));
      float Sv = reds[tid]*__expf(m0-M) + reds[256+tid]*__expf(m1-M)
               + reds[512+tid]*__expf(m2-M) + reds[768+tid]*__expf(m3-M);
      long row = (long)bm*256 + tid;
      pmax[row*NCHUNK + bn] = M;
      psum[row*NCHUNK + bn] = Sv;
    }
  } else {
    #pragma unroll
    for (int m=0;m<8;++m)
      #pragma unroll
      for (int n=0;n<4;++n) {
        long c = colbase + n*16 + l15;
        #pragma unroll
        for (int q_=0;q_<4;++q_) {
          long rr = rowbase + m*16 + g*4 + q_;
          float v = acc[m][n][q_];
          if constexpr (EPI == EPI_F32) {
            outf[(long)bz*sOb + rr*ldo + c] = v;
          } else if constexpr (EPI == EPI_BF16) {
            outb[(long)bz*sOb + rr*ldo + c] = (bf16)v;
          } else if constexpr (EPI == EPI_BIAS_RELU_BF16) {
            outb[rr*ldo + c] = (bf16)fmaxf(v + bias[c], 0.f);
          } else if constexpr (EPI == EPI_BIAS_RES_BF16) {
            outb[rr*ldo + c] = (bf16)(v + bias[c] + res[rr*ldr + c]);
          } else if constexpr (EPI == EPI_RES_F32) {
            outf[(long)bz*sOb + rr*ldo + c] = v + res[(long)bz*sRb + rr*ldr + c];
          }
        }
      }
  }
}

// ---------------- loss pass 1 ----------------
__global__ __launch_bounds__(256)
void loss1_kernel(const float* __restrict__ pmax, const float* __restrict__ psum,
                  const float* __restrict__ logits, const int* __restrict__ targets,
                  float* __restrict__ rowloss) {
  int row = blockIdx.x;
  int tid = threadIdx.x;
  int lane = tid & 63, wv = tid >> 6;
  float cm = (tid < NCHUNK) ? pmax[(long)row*NCHUNK + tid] : -1e30f;
  float cs = (tid < NCHUNK) ? psum[(long)row*NCHUNK + tid] : 0.f;
  float mx = cm;
  #pragma unroll
  for (int m=32;m>=1;m>>=1) mx = fmaxf(mx, __shfl_xor(mx, m));
  __shared__ float rm[4];
  if (lane == 0) rm[wv] = mx;
  __syncthreads();
  float M = fmaxf(fmaxf(rm[0],rm[1]), fmaxf(rm[2],rm[3]));
  float sc = cs * __expf(cm - M);
  #pragma unroll
  for (int m=32;m>=1;m>>=1) sc += __shfl_xor(sc, m);
  __shared__ float rs_[4];
  if (lane == 0) rs_[wv] = sc;
  __syncthreads();
  if (tid == 0) {
    float Sv = rs_[0]+rs_[1]+rs_[2]+rs_[3];
    float lse = M + logf(Sv);
    int tgt = targets[row];
    float lg = logits[(long)row*NV + tgt];
    rowloss[row] = lse - lg;
  }
}

// ---------------- loss pass 2 ----------------
__global__ __launch_bounds__(256)
void loss2_kernel(const float* __restrict__ rowloss, float* __restrict__ out) {
  int tid = threadIdx.x;
  float s = 0.f;
  for (int i = tid; i < NROWS; i += 256) s += rowloss[i];
  #pragma unroll
  for (int m=32;m>=1;m>>=1) s += __shfl_xor(s, m);
  __shared__ float rs_[4];
  if ((tid & 63) == 0) rs_[tid>>6] = s;
  __syncthreads();
  if (tid == 0) out[0] = (rs_[0]+rs_[1]+rs_[2]+rs_[3]) * (1.f/NROWS);
}

// ---------------- launcher ----------------
extern "C" void kernel_launch(void* const* d_in, const int* in_sizes, int n_in,
                              void* d_out, int out_size, void* d_ws, size_t ws_size,
                              hipStream_t stream) {
  const int*   idx  = (const int*)d_in[0];
  const int*   tgt  = (const int*)d_in[1];
  const float* tok  = (const float*)d_in[2];
  const float* pos  = (const float*)d_in[3];
  const float* Wk   = (const float*)d_in[4];
  const float* Wq   = (const float*)d_in[5];
  const float* Wv   = (const float*)d_in[6];
  const float* W1   = (const float*)d_in[7];
  const float* b1   = (const float*)d_in[8];
  const float* W2   = (const float*)d_in[9];
  const float* b2   = (const float*)d_in[10];
  const float* g1   = (const float*)d_in[11];
  const float* be1  = (const float*)d_in[12];
  const float* g2   = (const float*)d_in[13];
  const float* be2  = (const float*)d_in[14];
  const float* Wlm  = (const float*)d_in[15];
  const float* blm  = (const float*)d_in[16];

  float* logits = (float*)d_out;
  float* loss   = logits + (long)NROWS*NV;

  char* w = (char*)d_ws;
  auto alloc = [&](size_t bytes) -> char* {
    char* p = w; w += (bytes + 255) & ~(size_t)255; return p;
  };
  bf16* wqkvb = (bf16*)alloc((size_t)3*NC*NC*2);   // [1536][512]: Wq,Wk,Wv stacked
  bf16* w1b   = (bf16*)alloc((size_t)4*NC*NC*2);
  bf16* w2b   = (bf16*)alloc((size_t)4*NC*NC*2);
  bf16* wlmb  = (bf16*)alloc((size_t)NV*NC*2);
  float* x0   = (float*)alloc((size_t)NROWS*NC*4);
  bf16* h1b   = (bf16*)alloc((size_t)NROWS*NC*2);
  bf16* qkvb  = (bf16*)alloc((size_t)NROWS*3*NC*2); // [8192][1536]
  bf16* vtb   = (bf16*)alloc((size_t)NROWS*NC*2);
  float* Sb   = (float*)alloc((size_t)NB*NT*NT*4);  // P (bf16) aliased inside
  float* x1   = (float*)alloc((size_t)NROWS*NC*4);
  bf16* h2b   = (bf16*)alloc((size_t)NROWS*NC*2);
  bf16* ffb   = (bf16*)alloc((size_t)NROWS*4*NC*2);
  bf16* x2b   = (bf16*)alloc((size_t)NROWS*NC*2);
  float* pmax = (float*)alloc((size_t)NROWS*NCHUNK*4);
  float* psum = (float*)alloc((size_t)NROWS*NCHUNK*4);
  float* rowloss = (float*)alloc((size_t)NROWS*4);

  hipFuncSetAttribute((const void*)gemm256<EPI_BF16,false,false,false>,
                      hipFuncAttributeMaxDynamicSharedMemorySize, SMEM_B);
  hipFuncSetAttribute((const void*)gemm256<EPI_F32,true,false,false>,
                      hipFuncAttributeMaxDynamicSharedMemorySize, SMEM_B);
  hipFuncSetAttribute((const void*)gemm256<EPI_RES_F32,false,true,false>,
                      hipFuncAttributeMaxDynamicSharedMemorySize, SMEM_B);
  hipFuncSetAttribute((const void*)gemm256<EPI_BIAS_RELU_BF16,false,false,true>,
                      hipFuncAttributeMaxDynamicSharedMemorySize, SMEM_B);
  hipFuncSetAttribute((const void*)gemm256<EPI_BIAS_RES_BF16,false,false,false>,
                      hipFuncAttributeMaxDynamicSharedMemorySize, SMEM_B);
  hipFuncSetAttribute((const void*)gemm256<EPI_LMHEAD,false,false,true>,
                      hipFuncAttributeMaxDynamicSharedMemorySize, SMEM_B);

  auto cvt = [&](const float* in, bf16* out, long n) {
    int n8 = (int)(n/8);
    int blocks = (n8 + 255)/256; if (blocks > 2048) blocks = 2048;
    cvt_kernel<<<blocks, 256, 0, stream>>>(in, out, n8);
  };
  cvt(Wq, wqkvb, (long)NC*NC);
  cvt(Wk, wqkvb + (long)NC*NC, (long)NC*NC);
  cvt(Wv, wqkvb + (long)2*NC*NC, (long)NC*NC);
  cvt(W1, w1b, (long)4*NC*NC);
  cvt(W2, w2b, (long)4*NC*NC);
  cvt(Wlm, wlmb, (long)NV*NC);

  embed_ln_kernel<<<NROWS, 64, 0, stream>>>(idx, tok, pos, g1, be1, x0, h1b);

  // fused QKV: qkv[8192][1536] = h1 * Wqkv^T
  gemm256<EPI_BF16><<<dim3(6,32,1), 512, SMEM_B, stream>>>(
      h1b, wqkvb, 8, NC, NC, 0, 0, nullptr, qkvb, 3*NC, 0,
      nullptr, nullptr, 0, 0, nullptr, nullptr);

  transpose_kernel<<<dim3(NT/64, NC/64, NB), 256, 0, stream>>>(qkvb + 2*NC, 3*NC, vtb);

  // S = q k^T (per batch), causal block skip
  gemm256<EPI_F32,true><<<dim3(8,8,NB), 512, SMEM_B, stream>>>(
      qkvb, qkvb + NC, 8, 3*NC, 3*NC, (long)NT*3*NC, (long)NT*3*NC,
      Sb, nullptr, NT, (long)NT*NT,
      nullptr, nullptr, 0, 0, nullptr, nullptr);

  softmax_kernel<<<NROWS, 256, 0, stream>>>(Sb);

  // x1 = x0 + P vT^T (per batch), causal K-limit
  gemm256<EPI_RES_F32,false,true><<<dim3(2,8,NB), 512, SMEM_B, stream>>>(
      (const bf16*)Sb, vtb, 32, 2*NT, NT, (long)NT*2*NT, (long)NC*NT,
      x1, nullptr, NC, (long)NT*NC,
      nullptr, x0, NC, (long)NT*NC, nullptr, nullptr);

  ln_kernel<<<NROWS, 64, 0, stream>>>(x1, g2, be2, h2b);

  // ff = relu(h2 W1^T + b1)  (bm-fast grid: W1 panel L2-resident)
  gemm256<EPI_BIAS_RELU_BF16,false,false,true><<<dim3(32,8,1), 512, SMEM_B, stream>>>(
      h2b, w1b, 8, NC, NC, 0, 0, nullptr, ffb, 4*NC, 0,
      b1, nullptr, 0, 0, nullptr, nullptr);

  // x2 = x1 + ff W2^T + b2
  gemm256<EPI_BIAS_RES_BF16><<<dim3(2,32,1), 512, SMEM_B, stream>>>(
      ffb, w2b, 32, 4*NC, 4*NC, 0, 0, nullptr, x2b, NC, 0,
      b2, x1, NC, 0, nullptr, nullptr);

  // logits + per-256-col-chunk (max,sumexp) partials
  // bm-fast grid (SWAP): all XCDs consume one Wlm 256-col panel at a time ->
  // panel fetched from HBM once (262KB, L2-resident), x2b L3-resident.
  gemm256<EPI_LMHEAD,false,false,true><<<dim3(32,NCHUNK,1), 512, SMEM_B, stream>>>(
      x2b, wlmb, 8, NC, NC, 0, 0, logits, nullptr, NV, 0,
      blm, nullptr, 0, 0, pmax, psum);

  loss1_kernel<<<NROWS, 256, 0, stream>>>(pmax, psum, logits, tgt, rowloss);
  loss2_kernel<<<1, 256, 0, stream>>>(rowloss, loss);
}